// Round 1
// 388.696 us; speedup vs baseline: 1.1100x; 1.1100x over previous
//
#include <hip/hip_runtime.h>
#include <math.h>

// ---------------------------------------------------------------------------
// HybridBERT4RecGNN forward on MI355X (gfx950), round 12.
//
// R11 counters: seq_transformer 118us, MfmaUtil 5.2%, VALUBusy 39.7%, HBM 1.2%
// -> VALU-bound on bf16-convert + gelu-fdiv + softmax LDS round-trip overhead.
// R12:
//  (a) f2b/packb via native __bf16 casts -> compiler emits v_cvt_pk_bf16_f32
//      (HW convert, pairs fused) instead of ~4-op RNE bit-twiddle.
//  (b) gelu as x*sigmoid(2u) with v_rcp_f32; softmax 1/sum via v_rcp_f32
//      (removes IEEE fdiv sequences from the hot path).
//  (c) softmax fully in-register: score MFMA output already has each q-row's
//      64 keys inside one 16-lane quad -> intra-quad butterflies for max/sum;
//      only final P is written to LDS (for the ctx transpose). Deletes the
//      S->LDS->reg->LDS round trip (16 f2b + 16 b2f + 16 ds ops/head/thread).
//  (d) launch_bounds (256,6)->(256,3): LDS caps occupancy at 3 blocks/CU
//      anyway; frees VGPR headroom for the in-register softmax (no spill).
//  (e) GNN: avgh only read at seq-referenced nodes (~40%). Flag them in
//      cvt_hist (byte store), early-out gnn_gather_avg on unflagged nodes
//      (-60% of its edge gathers).
// ---------------------------------------------------------------------------

typedef __attribute__((ext_vector_type(8))) short bf16x8;
typedef __attribute__((ext_vector_type(4))) float f32x4;

#define SD   64
#define SS   50
#define NBLK 2
#define PH   72    // LDS pitch in halves (144 B, 16B-aligned rows, 2-way banks max)

__device__ __forceinline__ short f2b(float f) {  // fp32 -> bf16 RNE (HW cvt)
  union { __bf16 h; short s; } u;
  u.h = (__bf16)f;
  return u.s;
}
__device__ __forceinline__ float b2f(short s) {
  union { unsigned u; float f; } v;
  v.u = ((unsigned)(unsigned short)s) << 16;
  return v.f;
}
__device__ __forceinline__ unsigned packb(float a, float b) {
  union { __bf16 h; unsigned short s; } ua, ub;
  ua.h = (__bf16)a; ub.h = (__bf16)b;
  return (unsigned)ua.s | ((unsigned)ub.s << 16);
}
__device__ __forceinline__ float wred_sum(float v) {
#pragma unroll
  for (int o = 32; o > 0; o >>= 1) v += __shfl_xor(v, o, 64);
  return v;
}
__device__ __forceinline__ float2 wred_sum2(float a, float b) {
#pragma unroll
  for (int o = 32; o > 0; o >>= 1) {
    a += __shfl_xor(a, o, 64);
    b += __shfl_xor(b, o, 64);
  }
  return make_float2(a, b);
}
// gelu(x) = 0.5x(1+tanh(u)) = x * sigmoid(2u);  sigmoid via v_rcp_f32.
__device__ __forceinline__ float gelu_fast(float x) {
  float u = 0.7978845608028654f * x * (1.0f + 0.044715f * x * x);
  float e = __expf(-2.f * u);
  return x * __builtin_amdgcn_rcpf(1.0f + e);
}

__device__ __forceinline__ bf16x8 ldB(const short* __restrict__ Wb, int tile, int lane) {
  return *(const bf16x8*)(Wb + ((size_t)tile * 64 + lane) * 8);
}

// [own 16 rows x K=64] @ [64x64] -> D own rows. A from LDS bf16 pitch PH.
__device__ __forceinline__ void mm64(const short* A, const short* __restrict__ Wb,
                                     int arow, int quad, int lane, f32x4 o4[4]) {
  bf16x8 a0 = *(const bf16x8*)(A + arow * PH + quad * 8);
  bf16x8 a1 = *(const bf16x8*)(A + arow * PH + 32 + quad * 8);
#pragma unroll
  for (int nt = 0; nt < 4; ++nt) {
    f32x4 acc = {0.f, 0.f, 0.f, 0.f};
    acc = __builtin_amdgcn_mfma_f32_16x16x32_bf16(a0, ldB(Wb, 0 * 4 + nt, lane), acc, 0, 0, 0);
    acc = __builtin_amdgcn_mfma_f32_16x16x32_bf16(a1, ldB(Wb, 1 * 4 + nt, lane), acc, 0, 0, 0);
    o4[nt] = acc;
  }
}

// LN over 64 cols of D-layout values + residual from xh + optional bias.
// Intra-wave only (16-lane quad butterflies).
__device__ __forceinline__ void ln_epilogue(f32x4 o4[4], short* xh,
                                            const float* __restrict__ g,
                                            const float* __restrict__ bta,
                                            const float* __restrict__ extrab,
                                            int mt, int quad, int c0) {
  float vals[4][4];
  float s1[4] = {0.f, 0.f, 0.f, 0.f}, s2[4] = {0.f, 0.f, 0.f, 0.f};
#pragma unroll
  for (int nt = 0; nt < 4; ++nt) {
    int c = nt * 16 + c0;
    float eb = extrab ? extrab[c] : 0.f;
#pragma unroll
    for (int r = 0; r < 4; ++r) {
      int row = mt * 16 + quad * 4 + r;
      float v = o4[nt][r] + b2f(xh[row * PH + c]) + eb;
      vals[nt][r] = v;
      s1[r] += v;
      s2[r] += v * v;
    }
  }
#pragma unroll
  for (int o = 1; o < 16; o <<= 1) {
#pragma unroll
    for (int r = 0; r < 4; ++r) {
      s1[r] += __shfl_xor(s1[r], o, 64);
      s2[r] += __shfl_xor(s2[r], o, 64);
    }
  }
  float mv[4], rv[4];
#pragma unroll
  for (int r = 0; r < 4; ++r) {
    float m = s1[r] * (1.f / 64);
    float var = fmaxf(s2[r] * (1.f / 64) - m * m, 0.f);
    mv[r] = m;
    rv[r] = rsqrtf(var + 1e-5f);
  }
#pragma unroll
  for (int nt = 0; nt < 4; ++nt) {
    int c = nt * 16 + c0;
    float gv = g[c], bv = bta[c];
#pragma unroll
    for (int r = 0; r < 4; ++r) {
      int row = mt * 16 + quad * 4 + r;
      xh[row * PH + c] = f2b((vals[nt][r] - mv[r]) * rv[r] * gv + bv);
    }
  }
}

// ---------------------------------------------------------------------------
// Combined weight prep (unchanged)
// ---------------------------------------------------------------------------
__global__ void prep_all(const float* __restrict__ pw, const float* __restrict__ wq,
                         const float* __restrict__ wk, const float* __restrict__ wv,
                         const float* __restrict__ wo, const float* __restrict__ w1,
                         const float* __restrict__ w2,
                         short* __restrict__ pwB, short* __restrict__ wqB,
                         short* __restrict__ wkB, short* __restrict__ wvB,
                         short* __restrict__ woB, short* __restrict__ w1B,
                         short* __restrict__ w2B) {
  int tid = blockIdx.x * blockDim.x + threadIdx.x;
  int lane = tid & 63;
  int tile = tid >> 6;
  const float* W; short* out; int K, N, base;
  if (tile < 8)        { W = pw; out = pwB; K = 64;  N = 64;  base = 0; }
  else if (tile < 24)  { W = wq; out = wqB; K = 64;  N = 64;  base = 8; }
  else if (tile < 40)  { W = wk; out = wkB; K = 64;  N = 64;  base = 24; }
  else if (tile < 56)  { W = wv; out = wvB; K = 64;  N = 64;  base = 40; }
  else if (tile < 72)  { W = wo; out = woB; K = 64;  N = 64;  base = 56; }
  else if (tile < 136) { W = w1; out = w1B; K = 64;  N = 256; base = 72; }
  else if (tile < 200) { W = w2; out = w2B; K = 256; N = 64;  base = 136; }
  else return;
  int lt = tile - base;
  int KT = K / 32, NT = N / 16;
  int nt = lt % NT; lt /= NT;
  int kt = lt % KT; lt /= KT;
  int m = lt;
  const float* Wm = W + (size_t)m * K * N;
  int kbase = kt * 32 + ((lane >> 4) * 8);
  int n = nt * 16 + (lane & 15);
  short v[8];
#pragma unroll
  for (int j = 0; j < 8; ++j) v[j] = f2b(Wm[(size_t)(kbase + j) * N + n]);
  *(bf16x8*)(out + ((size_t)(tile - base) * 64 + lane) * 8) = *(bf16x8*)v;
}

// fp32 table -> packed bf16 pairs, fused with dst-degree histogram and
// seq-referenced-node flagging (avgh is only read at flagged nodes).
__global__ void cvt_hist(const float* __restrict__ in, unsigned* __restrict__ out,
                         int n32, const int* __restrict__ dst, int* __restrict__ cnt,
                         int E, const int* __restrict__ seq,
                         unsigned char* __restrict__ flags, int BS) {
  int i = blockIdx.x * blockDim.x + threadIdx.x;
  if (i < n32) {
    float2 f = ((const float2*)in)[i];
    out[i] = packb(f.x, f.y);
  }
  if (i < E) atomicAdd(&cnt[dst[i]], 1);
  if (i < BS) flags[seq[i]] = 1;
}

// ---------------------------------------------------------------------------
// GNN CSR scan/build (unchanged)
// ---------------------------------------------------------------------------
__global__ void gnn_chunk_sums(const int* __restrict__ cnt, int* __restrict__ bsum) {
  __shared__ int ssum;
  if (threadIdx.x == 0) ssum = 0;
  __syncthreads();
  int base = blockIdx.x * 1024 + threadIdx.x * 4;
  int s = cnt[base] + cnt[base + 1] + cnt[base + 2] + cnt[base + 3];
#pragma unroll
  for (int o = 32; o > 0; o >>= 1) s += __shfl_xor(s, o, 64);
  if ((threadIdx.x & 63) == 0) atomicAdd(&ssum, s);
  __syncthreads();
  if (threadIdx.x == 0) bsum[blockIdx.x] = ssum;
}

__global__ void gnn_scan_bsum(int* __restrict__ bsum, int nch) {
  __shared__ int sb[128];
  int t = threadIdx.x;
  if (t < nch) sb[t] = bsum[t];
  __syncthreads();
  if (t == 0) {
    int a = 0;
    for (int i = 0; i < nch; ++i) { int v = sb[i]; sb[i] = a; a += v; }
  }
  __syncthreads();
  if (t < nch) bsum[t] = sb[t];
}

__global__ void gnn_chunk_scan(const int* __restrict__ cnt, const int* __restrict__ bofs,
                               int* __restrict__ rp, int* __restrict__ wp, int Nn) {
  __shared__ int wsum[4];
  int t = threadIdx.x, lane = t & 63, wv = t >> 6;
  int base = blockIdx.x * 1024 + t * 4;
  int c0 = cnt[base], c1 = cnt[base + 1], c2 = cnt[base + 2], c3 = cnt[base + 3];
  int s = c0 + c1 + c2 + c3;
  int x = s;
#pragma unroll
  for (int o = 1; o < 64; o <<= 1) {
    int y = __shfl_up(x, o, 64);
    if (lane >= o) x += y;
  }
  if (lane == 63) wsum[wv] = x;
  __syncthreads();
  int wo = 0;
#pragma unroll
  for (int i = 0; i < 4; ++i) if (i < wv) wo += wsum[i];
  int excl = bofs[blockIdx.x] + wo + (x - s);
  int p[4];
  p[0] = excl; p[1] = p[0] + c0; p[2] = p[1] + c1; p[3] = p[2] + c2;
#pragma unroll
  for (int j = 0; j < 4; ++j) {
    int idx = base + j;
    if (idx <= Nn) rp[idx] = p[j];
    if (idx < Nn) wp[idx] = p[j];
  }
}

__global__ void gnn_build(const int* __restrict__ src, const int* __restrict__ dst,
                          const float* __restrict__ ew, int* __restrict__ wp,
                          int2* __restrict__ ep, int E) {
  int e = blockIdx.x * blockDim.x + threadIdx.x;
  if (e >= E) return;
  int pos = atomicAdd(&wp[dst[e]], 1);
  ep[pos] = make_int2(src[e], __float_as_int(ew[e]));
}

__global__ void gnn_gather1(const unsigned* __restrict__ xinh,
                            const int* __restrict__ rp, const int2* __restrict__ ep,
                            unsigned* __restrict__ xouth, int Nn) {
  int n = blockIdx.x * 8 + (threadIdx.x >> 5);
  int hl = threadIdx.x & 31;
  if (n >= Nn) return;
  int beg = rp[n], end = rp[n + 1];
  float a0 = 0.f, a1 = 0.f;
  int e = beg;
  for (; e + 2 <= end; e += 2) {
    int2 e0 = ep[e], e1 = ep[e + 1];
    float w0 = __int_as_float(e0.y), w1 = __int_as_float(e1.y);
    unsigned p0 = xinh[(size_t)e0.x * 32 + hl];
    unsigned p1 = xinh[(size_t)e1.x * 32 + hl];
    a0 += b2f((short)(p0 & 0xFFFF)) * w0 + b2f((short)(p1 & 0xFFFF)) * w1;
    a1 += b2f((short)(p0 >> 16)) * w0 + b2f((short)(p1 >> 16)) * w1;
  }
  for (; e < end; ++e) {
    int2 ee = ep[e];
    float w = __int_as_float(ee.y);
    unsigned p = xinh[(size_t)ee.x * 32 + hl];
    a0 += b2f((short)(p & 0xFFFF)) * w;
    a1 += b2f((short)(p >> 16)) * w;
  }
  xouth[(size_t)n * 32 + hl] = packb(a0, a1);
}

__global__ void gnn_gather_avg(const unsigned* __restrict__ x1h,
                               const int* __restrict__ rp, const int2* __restrict__ ep,
                               const float* __restrict__ gnn,
                               unsigned* __restrict__ avgh, int Nn,
                               const unsigned char* __restrict__ flags) {
  int n = blockIdx.x * 8 + (threadIdx.x >> 5);
  int hl = threadIdx.x & 31;
  if (n >= Nn) return;
  if (!flags[n]) return;   // avgh[n] is never read by the transformer
  int beg = rp[n], end = rp[n + 1];
  float a0 = 0.f, a1 = 0.f;
  int e = beg;
  for (; e + 2 <= end; e += 2) {
    int2 e0 = ep[e], e1 = ep[e + 1];
    float w0 = __int_as_float(e0.y), w1 = __int_as_float(e1.y);
    unsigned p0 = x1h[(size_t)e0.x * 32 + hl];
    unsigned p1 = x1h[(size_t)e1.x * 32 + hl];
    a0 += b2f((short)(p0 & 0xFFFF)) * w0 + b2f((short)(p1 & 0xFFFF)) * w1;
    a1 += b2f((short)(p0 >> 16)) * w0 + b2f((short)(p1 >> 16)) * w1;
  }
  for (; e < end; ++e) {
    int2 ee = ep[e];
    float w = __int_as_float(ee.y);
    unsigned p = x1h[(size_t)ee.x * 32 + hl];
    a0 += b2f((short)(p & 0xFFFF)) * w;
    a1 += b2f((short)(p >> 16)) * w;
  }
  float2 g = ((const float2*)gnn)[(size_t)n * 32 + hl];
  unsigned own = x1h[(size_t)n * 32 + hl];
  float v0 = (g.x + b2f((short)(own & 0xFFFF)) + a0) * (1.f / 3.f);
  float v1 = (g.y + b2f((short)(own >> 16)) + a1) * (1.f / 3.f);
  avgh[(size_t)n * 32 + hl] = packb(v0, v1);
}

// fallback helpers
__global__ void gnn_scatter(const float* __restrict__ xin,
                            const int* __restrict__ src,
                            const int* __restrict__ dst,
                            const float* __restrict__ ew,
                            float* __restrict__ xout, int E) {
  int gid = blockIdx.x * blockDim.x + threadIdx.x;
  int e = gid >> 6;
  int d = gid & 63;
  if (e >= E) return;
  atomicAdd(&xout[(size_t)dst[e] * SD + d], xin[(size_t)src[e] * SD + d] * ew[e]);
}
__global__ void avg_from_f32(const float* __restrict__ gnn, const float* __restrict__ g1,
                             const float* __restrict__ g2, unsigned* __restrict__ avgh,
                             int n32) {
  int i = blockIdx.x * blockDim.x + threadIdx.x;
  if (i >= n32) return;
  float2 a = ((const float2*)gnn)[i];
  float2 b = ((const float2*)g1)[i];
  float2 c = ((const float2*)g2)[i];
  avgh[i] = packb((a.x + b.x + c.x) * (1.f / 3.f), (a.y + b.y + c.y) * (1.f / 3.f));
}

// ---------------------------------------------------------------------------
// MFMA transformer, row-ownership version. 256 threads = 4 waves; wave mt
// owns rows [mt*16, mt*16+16). Softmax fully in-register (score MFMA output
// keeps each q-row's 64 keys inside one 16-lane quad). 2 barriers/layer.
// LDS: 5 x 9216 + 256 = 46,336 B -> 3 blocks/CU (LDS-bound), hence
// launch_bounds min-waves 3/EU to free VGPR headroom.
// ---------------------------------------------------------------------------
__global__ __launch_bounds__(256, 3)
void seq_transformer(const int* __restrict__ seq, const int* __restrict__ lengths,
                     const float* __restrict__ bert, const short* __restrict__ avgh,
                     const float* __restrict__ pbias, const float* __restrict__ pos,
                     const short* __restrict__ pwB, const short* __restrict__ wqB,
                     const short* __restrict__ wkB, const short* __restrict__ wvB,
                     const short* __restrict__ woB, const short* __restrict__ w1B,
                     const short* __restrict__ w2B,
                     const float* __restrict__ b1, const float* __restrict__ b2,
                     const float* __restrict__ ln1g, const float* __restrict__ ln1b,
                     const float* __restrict__ ln2g, const float* __restrict__ ln2b,
                     const float* __restrict__ lnfg, const float* __restrict__ lnfb,
                     float* __restrict__ out) {
  __shared__ short xh[64 * PH];   // x
  __shared__ short qh[64 * PH];   // Q -> ctx -> ffn-h (own rows only)
  __shared__ short kh[64 * PH];   // K (cross-wave read)
  __shared__ short vt[64 * PH];   // V^T (cross-wave read)
  __shared__ short s0[64 * PH];   // P (own rows only; softmax is in-register)
  __shared__ int   sidx[64];

  const int t = threadIdx.x;
  const int lane = t & 63;
  const int mt = t >> 6;
  const int quad = lane >> 4;
  const int c0 = lane & 15;
  const int b = blockIdx.x;
  const int arow = mt * 16 + c0;   // own-row index for A-frags

  if (t < 64) sidx[t] = (t < SS) ? seq[b * SS + t] : 0;
  __syncthreads();   // barrier 1 (sidx)

  const int len = lengths[b];
  const float alpha = (len <= 10) ? 0.3f : ((len >= 50) ? 0.7f : 0.5f);
  const float isq = 0.17677669529663687f;  // 1/sqrt(32)

  // key mask bias per nt-tile (constant across layers/heads): key = nt*16+c0
  float kbias[4];
#pragma unroll
  for (int nt = 0; nt < 4; ++nt) {
    int key = nt * 16 + c0;
    kbias[nt] = (key < SS && sidx[key] != 0) ? 0.f : -1e9f;
  }

  // ---- phase 0a: fused GNN-average rows (own rows) -> qh
#pragma unroll
  for (int ir = 0; ir < 16; ++ir) {
    int s = mt * 16 + ir;
    short v = 0;
    if (s < SS) v = avgh[(size_t)sidx[s] * SD + lane];
    qh[s * PH + lane] = v;
  }

  // ---- phase 0b: gnn projection + blend + pos -> xh (own rows; no barrier:
  //      qh own rows written by this wave)
  {
    f32x4 o4[4];
    mm64(qh, pwB, arow, quad, lane, o4);
#pragma unroll
    for (int nt = 0; nt < 4; ++nt) {
      int c = nt * 16 + c0;
      float pbv = pbias[c];
#pragma unroll
      for (int r = 0; r < 4; ++r) {
        int row = mt * 16 + quad * 4 + r;
        short ov = 0;
        if (row < SS) {
          float g = o4[nt][r] + pbv;
          float xv = alpha * bert[(size_t)sidx[row] * SD + c] +
                     (1.f - alpha) * g + pos[row * SD + c];
          ov = f2b(xv);
        }
        xh[row * PH + c] = ov;
      }
    }
  }

#pragma unroll 1
  for (int blk = 0; blk < NBLK; ++blk) {
    const short* Wq = wqB + blk * 4096;
    const short* Wk = wkB + blk * 4096;
    const short* Wv = wvB + blk * 4096;
    const short* Wo = woB + blk * 4096;
    const short* W1 = w1B + blk * 16384;
    const short* W2 = w2B + blk * 16384;

    __syncthreads();   // layer-top: kh/vt safe to rewrite (prev readers done)

    // ---- Q -> qh, K -> kh (own rows), V -> vt (own seq-columns, transposed)
    {
      f32x4 o4[4];
      mm64(xh, Wq, arow, quad, lane, o4);
#pragma unroll
      for (int nt = 0; nt < 4; ++nt) {
        int c = nt * 16 + c0;
#pragma unroll
        for (int r = 0; r < 4; ++r) qh[(mt * 16 + quad * 4 + r) * PH + c] = f2b(o4[nt][r]);
      }
      mm64(xh, Wk, arow, quad, lane, o4);
#pragma unroll
      for (int nt = 0; nt < 4; ++nt) {
        int c = nt * 16 + c0;
#pragma unroll
        for (int r = 0; r < 4; ++r) kh[(mt * 16 + quad * 4 + r) * PH + c] = f2b(o4[nt][r]);
      }
      mm64(xh, Wv, arow, quad, lane, o4);
#pragma unroll
      for (int nt = 0; nt < 4; ++nt) {
        int dim = nt * 16 + c0;
        unsigned p0 = packb(o4[nt][0], o4[nt][1]);
        unsigned p1 = packb(o4[nt][2], o4[nt][3]);
        *(uint2*)(vt + (size_t)dim * PH + mt * 16 + quad * 4) = make_uint2(p0, p1);
      }
    }
    __syncthreads();   // kh/vt visible to all waves

    // ---- per-head: scores -> in-register softmax -> P -> ctx (no barriers)
#pragma unroll
    for (int h = 0; h < 2; ++h) {
      // scores for own q-rows; q-row (quad,r)'s 64 keys live across the
      // quad's 16 lanes (c0) x 4 regs (nt) -> intra-quad reductions.
      {
        bf16x8 aq = *(const bf16x8*)(qh + arow * PH + h * 32 + quad * 8);
        float p[4][4];   // [nt][r]
        float mx[4], sm[4];
#pragma unroll
        for (int nt = 0; nt < 4; ++nt) {
          int key = nt * 16 + c0;
          bf16x8 bk = *(const bf16x8*)(kh + key * PH + h * 32 + quad * 8);
          f32x4 acc = {0.f, 0.f, 0.f, 0.f};
          acc = __builtin_amdgcn_mfma_f32_16x16x32_bf16(aq, bk, acc, 0, 0, 0);
#pragma unroll
          for (int r = 0; r < 4; ++r) p[nt][r] = fmaf(acc[r], isq, kbias[nt]);
        }
#pragma unroll
        for (int r = 0; r < 4; ++r)
          mx[r] = fmaxf(fmaxf(p[0][r], p[1][r]), fmaxf(p[2][r], p[3][r]));
#pragma unroll
        for (int o = 1; o < 16; o <<= 1)
#pragma unroll
          for (int r = 0; r < 4; ++r) mx[r] = fmaxf(mx[r], __shfl_xor(mx[r], o, 64));
#pragma unroll
        for (int r = 0; r < 4; ++r) sm[r] = 0.f;
#pragma unroll
        for (int nt = 0; nt < 4; ++nt)
#pragma unroll
          for (int r = 0; r < 4; ++r) {
            float e = __expf(p[nt][r] - mx[r]);
            p[nt][r] = e;
            sm[r] += e;
          }
#pragma unroll
        for (int o = 1; o < 16; o <<= 1)
#pragma unroll
          for (int r = 0; r < 4; ++r) sm[r] += __shfl_xor(sm[r], o, 64);
#pragma unroll
        for (int r = 0; r < 4; ++r) {
          float inv = __builtin_amdgcn_rcpf(sm[r]);
          int q = mt * 16 + quad * 4 + r;
#pragma unroll
          for (int nt = 0; nt < 4; ++nt)
            s0[q * PH + nt * 16 + c0] = f2b(p[nt][r] * inv);
        }
      }
      // ctx_h = P V_h -> overwrite qh own rows, cols h*32..h*32+31
      {
        bf16x8 a0 = *(const bf16x8*)(s0 + arow * PH + quad * 8);
        bf16x8 a1 = *(const bf16x8*)(s0 + arow * PH + 32 + quad * 8);
#pragma unroll
        for (int nt = 0; nt < 2; ++nt) {
          int dim = h * 32 + nt * 16 + c0;
          bf16x8 b0 = *(const bf16x8*)(vt + (size_t)dim * PH + quad * 8);
          bf16x8 b1v = *(const bf16x8*)(vt + (size_t)dim * PH + 32 + quad * 8);
          f32x4 acc = {0.f, 0.f, 0.f, 0.f};
          acc = __builtin_amdgcn_mfma_f32_16x16x32_bf16(a0, b0, acc, 0, 0, 0);
          acc = __builtin_amdgcn_mfma_f32_16x16x32_bf16(a1, b1v, acc, 0, 0, 0);
#pragma unroll
          for (int r = 0; r < 4; ++r)
            qh[(mt * 16 + quad * 4 + r) * PH + dim] = f2b(acc[r]);
        }
      }
    }

    // ---- O-projection + residual + LN1 -> xh (own rows)
    {
      f32x4 o4[4];
      mm64(qh, Wo, arow, quad, lane, o4);
      ln_epilogue(o4, xh, ln1g + blk * SD, ln1b + blk * SD, nullptr, mt, quad, c0);
    }

    // ---- FFN, own rows, no barriers (intra-wave LDS ordering)
    f32x4 facc[4];
#pragma unroll
    for (int nt = 0; nt < 4; ++nt) facc[nt] = (f32x4){0.f, 0.f, 0.f, 0.f};
#pragma unroll 1
    for (int c = 0; c < 4; ++c) {
      {
        bf16x8 a0 = *(const bf16x8*)(xh + arow * PH + quad * 8);
        bf16x8 a1 = *(const bf16x8*)(xh + arow * PH + 32 + quad * 8);
#pragma unroll
        for (int nt = 0; nt < 4; ++nt) {
          int ntg = c * 4 + nt;
          f32x4 acc = {0.f, 0.f, 0.f, 0.f};
          acc = __builtin_amdgcn_mfma_f32_16x16x32_bf16(a0, ldB(W1, 0 * 16 + ntg, lane), acc, 0, 0, 0);
          acc = __builtin_amdgcn_mfma_f32_16x16x32_bf16(a1, ldB(W1, 1 * 16 + ntg, lane), acc, 0, 0, 0);
          int cc = nt * 16 + c0;
          float b1v = b1[blk * 256 + c * 64 + cc];
#pragma unroll
          for (int r = 0; r < 4; ++r)
            qh[(mt * 16 + quad * 4 + r) * PH + cc] = f2b(gelu_fast(acc[r] + b1v));
        }
      }
      {
        bf16x8 a0 = *(const bf16x8*)(qh + arow * PH + quad * 8);
        bf16x8 a1 = *(const bf16x8*)(qh + arow * PH + 32 + quad * 8);
#pragma unroll
        for (int nt = 0; nt < 4; ++nt) {
          facc[nt] = __builtin_amdgcn_mfma_f32_16x16x32_bf16(a0, ldB(W2, (2 * c) * 4 + nt, lane), facc[nt], 0, 0, 0);
          facc[nt] = __builtin_amdgcn_mfma_f32_16x16x32_bf16(a1, ldB(W2, (2 * c + 1) * 4 + nt, lane), facc[nt], 0, 0, 0);
        }
      }
    }

    // ---- residual + b2 + LN2 -> xh (own rows)
    ln_epilogue(facc, xh, ln2g + blk * SD, ln2b + blk * SD, b2 + blk * SD, mt, quad, c0);
  }
  __syncthreads();   // final: xh fully written by all waves

  // ---- final LN + gather row (lengths-1)
  if (mt == 0) {
    int sl = len - 1;
    float val = b2f(xh[sl * PH + lane]);
    float2 ss = wred_sum2(val, val * val);
    float m = ss.x * (1.f / 64);
    float var = fmaxf(ss.y * (1.f / 64) - m * m, 0.f);
    float rs = rsqrtf(var + 1e-5f);
    out[b * SD + lane] = (val - m) * rs * lnfg[lane] + lnfb[lane];
  }
}

// ---------------------------------------------------------------------------
extern "C" void kernel_launch(void* const* d_in, const int* in_sizes, int n_in,
                              void* d_out, int out_size, void* d_ws, size_t ws_size,
                              hipStream_t stream) {
  const int*   seq   = (const int*)d_in[0];
  const int*   lens  = (const int*)d_in[1];
  const int*   ei    = (const int*)d_in[2];
  const float* ew    = (const float*)d_in[3];
  const float* bert  = (const float*)d_in[4];
  const float* gnn   = (const float*)d_in[5];
  const float* pw    = (const float*)d_in[6];
  const float* pb    = (const float*)d_in[7];
  const float* pos   = (const float*)d_in[8];
  const float* wq    = (const float*)d_in[9];
  const float* wk    = (const float*)d_in[10];
  const float* wv    = (const float*)d_in[11];
  const float* wo    = (const float*)d_in[12];
  const float* w1    = (const float*)d_in[13];
  const float* b1    = (const float*)d_in[14];
  const float* w2    = (const float*)d_in[15];
  const float* b2    = (const float*)d_in[16];
  const float* ln1g  = (const float*)d_in[17];
  const float* ln1b  = (const float*)d_in[18];
  const float* ln2g  = (const float*)d_in[19];
  const float* ln2b  = (const float*)d_in[20];
  const float* lnfg  = (const float*)d_in[21];
  const float* lnfb  = (const float*)d_in[22];
  float* out = (float*)d_out;

  const int E = in_sizes[2] / 2;          // 1,000,000
  const int B = in_sizes[0] / SS;         // 1024
  const int N = in_sizes[4] / SD;         // 100,001
  const int BS = B * SS;                  // 51,200 seq entries

  const int* esrc = ei;
  const int* edst = ei + E;

  // ---- workspace layout
  short* pwB = (short*)d_ws;              // 4096 halves
  short* wqB = pwB + 4096;                // 8192
  short* wkB = wqB + 8192;
  short* wvB = wkB + 8192;
  short* woB = wvB + 8192;
  short* w1B = woB + 8192;                // 32768
  short* w2B = w1B + 32768;               // 32768
  unsigned* gnnh = (unsigned*)(w2B + 32768);   // N*32 uints (bf16 pairs)
  unsigned* g1xh = gnnh + (size_t)N * 32;
  unsigned* avgh = g1xh + (size_t)N * 32;
  const int NCH = (N + 1023) >> 10;
  const int PADN = NCH << 10;
  int* cnt  = (int*)(avgh + (size_t)N * 32);
  const int NF = (N + 255) & ~255;        // flag bytes, padded
  unsigned char* flags = (unsigned char*)(cnt + PADN);
  int* bsum = (int*)(flags + NF);
  int* rp   = bsum + 128;
  int* wp   = rp + (N + 1);
  int2* ep = (int2*)((((size_t)(wp + N)) + 15) & ~(size_t)15);
  size_t need = (size_t)((char*)(ep + E) - (char*)d_ws);

  // fallback fp32 tables (overlay the CSR/scan region)
  float* g1x = (float*)cnt;
  float* g2x = g1x + (size_t)N * SD;
  size_t need_fb = (size_t)((char*)(g2x + (size_t)N * SD) - (char*)d_ws);

  // ---- weight prep (1 launch)
  prep_all<<<50, 256, 0, stream>>>(pw, wq, wk, wv, wo, w1, w2,
                                   pwB, wqB, wkB, wvB, woB, w1B, w2B);

  const int n32 = N * 32;
  if (ws_size >= need && NCH <= 128) {
    hipMemsetAsync(cnt, 0, (size_t)PADN * sizeof(int) + NF, stream);
    cvt_hist<<<(n32 + 255) / 256, 256, 0, stream>>>(gnn, gnnh, n32, edst, cnt, E,
                                                    seq, flags, BS);
    gnn_chunk_sums<<<NCH, 256, 0, stream>>>(cnt, bsum);
    gnn_scan_bsum<<<1, 128, 0, stream>>>(bsum, NCH);
    gnn_chunk_scan<<<NCH, 256, 0, stream>>>(cnt, bsum, rp, wp, N);
    gnn_build<<<(E + 255) / 256, 256, 0, stream>>>(esrc, edst, ew, wp, ep, E);
    const int nb = (N + 7) / 8;
    gnn_gather1<<<nb, 256, 0, stream>>>(gnnh, rp, ep, g1xh, N);
    gnn_gather_avg<<<nb, 256, 0, stream>>>(g1xh, rp, ep, gnn, avgh, N, flags);
  } else if (ws_size >= need_fb) {
    hipMemsetAsync(g1x, 0, (size_t)2 * N * SD * sizeof(float), stream);
    const long total = (long)E * 64;
    const int sblocks = (int)((total + 255) / 256);
    gnn_scatter<<<sblocks, 256, 0, stream>>>(gnn, esrc, edst, ew, g1x, E);
    gnn_scatter<<<sblocks, 256, 0, stream>>>(g1x, esrc, edst, ew, g2x, E);
    avg_from_f32<<<(n32 + 255) / 256, 256, 0, stream>>>(gnn, g1x, g2x, avgh, n32);
  }

  seq_transformer<<<B, 256, 0, stream>>>(
      seq, lens, bert, (const short*)avgh, pb, pos,
      pwB, wqB, wkB, wvB, woB, w1B, w2B,
      b1, b2, ln1g, ln1b, ln2g, ln2b, lnfg, lnfb, out);
}

// Round 2
// 376.707 us; speedup vs baseline: 1.1453x; 1.0318x over previous
//
#include <hip/hip_runtime.h>
#include <math.h>

// ---------------------------------------------------------------------------
// HybridBERT4RecGNN forward on MI355X (gfx950), round 13.
//
// R12 counters: seq_transformer 83us (MfmaUtil 7.5%, VALUBusy 34.6%) -> at
// its structural latency floor. Wall 389us => ~306us in the GNN pipeline
// (below top-5 cutoff, spread over gather1/gather_avg/build).
// R13: gather kernels restructured from 1 half-wave per node walking edges
// SERIALLY (deg~10 -> ~5 dependent random 128B reads at L2/L3-miss latency)
// to one 64-lane wave per node as 8 edge-slots x 8 dim-lanes:
//   - 8 neighbor rows in flight per wave instruction (slot s handles edges
//     beg+s, beg+s+8, ...), per-lane chain ceil(10/8)=2.
//   - lane g reads uint4 = 8 bf16 dims; 8 lanes x 16B = coalesced 128B row.
//   - ep reads: 8 consecutive int2 = one 64B line per iteration.
//   - cross-slot combine: 3-step __shfl_xor(8/16/32); slot 0 stores uint4.
// Transformer + CSR build + scans unchanged to isolate the delta.
// ---------------------------------------------------------------------------

typedef __attribute__((ext_vector_type(8))) short bf16x8;
typedef __attribute__((ext_vector_type(4))) float f32x4;

#define SD   64
#define SS   50
#define NBLK 2
#define PH   72    // LDS pitch in halves (144 B, 16B-aligned rows, 2-way banks max)

__device__ __forceinline__ short f2b(float f) {  // fp32 -> bf16 RNE (HW cvt)
  union { __bf16 h; short s; } u;
  u.h = (__bf16)f;
  return u.s;
}
__device__ __forceinline__ float b2f(short s) {
  union { unsigned u; float f; } v;
  v.u = ((unsigned)(unsigned short)s) << 16;
  return v.f;
}
__device__ __forceinline__ unsigned packb(float a, float b) {
  union { __bf16 h; unsigned short s; } ua, ub;
  ua.h = (__bf16)a; ub.h = (__bf16)b;
  return (unsigned)ua.s | ((unsigned)ub.s << 16);
}
__device__ __forceinline__ float2 wred_sum2(float a, float b) {
#pragma unroll
  for (int o = 32; o > 0; o >>= 1) {
    a += __shfl_xor(a, o, 64);
    b += __shfl_xor(b, o, 64);
  }
  return make_float2(a, b);
}
// gelu(x) = 0.5x(1+tanh(u)) = x * sigmoid(2u);  sigmoid via v_rcp_f32.
__device__ __forceinline__ float gelu_fast(float x) {
  float u = 0.7978845608028654f * x * (1.0f + 0.044715f * x * x);
  float e = __expf(-2.f * u);
  return x * __builtin_amdgcn_rcpf(1.0f + e);
}

__device__ __forceinline__ bf16x8 ldB(const short* __restrict__ Wb, int tile, int lane) {
  return *(const bf16x8*)(Wb + ((size_t)tile * 64 + lane) * 8);
}

// [own 16 rows x K=64] @ [64x64] -> D own rows. A from LDS bf16 pitch PH.
__device__ __forceinline__ void mm64(const short* A, const short* __restrict__ Wb,
                                     int arow, int quad, int lane, f32x4 o4[4]) {
  bf16x8 a0 = *(const bf16x8*)(A + arow * PH + quad * 8);
  bf16x8 a1 = *(const bf16x8*)(A + arow * PH + 32 + quad * 8);
#pragma unroll
  for (int nt = 0; nt < 4; ++nt) {
    f32x4 acc = {0.f, 0.f, 0.f, 0.f};
    acc = __builtin_amdgcn_mfma_f32_16x16x32_bf16(a0, ldB(Wb, 0 * 4 + nt, lane), acc, 0, 0, 0);
    acc = __builtin_amdgcn_mfma_f32_16x16x32_bf16(a1, ldB(Wb, 1 * 4 + nt, lane), acc, 0, 0, 0);
    o4[nt] = acc;
  }
}

// LN over 64 cols of D-layout values + residual from xh + optional bias.
// Intra-wave only (16-lane quad butterflies).
__device__ __forceinline__ void ln_epilogue(f32x4 o4[4], short* xh,
                                            const float* __restrict__ g,
                                            const float* __restrict__ bta,
                                            const float* __restrict__ extrab,
                                            int mt, int quad, int c0) {
  float vals[4][4];
  float s1[4] = {0.f, 0.f, 0.f, 0.f}, s2[4] = {0.f, 0.f, 0.f, 0.f};
#pragma unroll
  for (int nt = 0; nt < 4; ++nt) {
    int c = nt * 16 + c0;
    float eb = extrab ? extrab[c] : 0.f;
#pragma unroll
    for (int r = 0; r < 4; ++r) {
      int row = mt * 16 + quad * 4 + r;
      float v = o4[nt][r] + b2f(xh[row * PH + c]) + eb;
      vals[nt][r] = v;
      s1[r] += v;
      s2[r] += v * v;
    }
  }
#pragma unroll
  for (int o = 1; o < 16; o <<= 1) {
#pragma unroll
    for (int r = 0; r < 4; ++r) {
      s1[r] += __shfl_xor(s1[r], o, 64);
      s2[r] += __shfl_xor(s2[r], o, 64);
    }
  }
  float mv[4], rv[4];
#pragma unroll
  for (int r = 0; r < 4; ++r) {
    float m = s1[r] * (1.f / 64);
    float var = fmaxf(s2[r] * (1.f / 64) - m * m, 0.f);
    mv[r] = m;
    rv[r] = rsqrtf(var + 1e-5f);
  }
#pragma unroll
  for (int nt = 0; nt < 4; ++nt) {
    int c = nt * 16 + c0;
    float gv = g[c], bv = bta[c];
#pragma unroll
    for (int r = 0; r < 4; ++r) {
      int row = mt * 16 + quad * 4 + r;
      xh[row * PH + c] = f2b((vals[nt][r] - mv[r]) * rv[r] * gv + bv);
    }
  }
}

// ---------------------------------------------------------------------------
// Combined weight prep (unchanged)
// ---------------------------------------------------------------------------
__global__ void prep_all(const float* __restrict__ pw, const float* __restrict__ wq,
                         const float* __restrict__ wk, const float* __restrict__ wv,
                         const float* __restrict__ wo, const float* __restrict__ w1,
                         const float* __restrict__ w2,
                         short* __restrict__ pwB, short* __restrict__ wqB,
                         short* __restrict__ wkB, short* __restrict__ wvB,
                         short* __restrict__ woB, short* __restrict__ w1B,
                         short* __restrict__ w2B) {
  int tid = blockIdx.x * blockDim.x + threadIdx.x;
  int lane = tid & 63;
  int tile = tid >> 6;
  const float* W; short* out; int K, N, base;
  if (tile < 8)        { W = pw; out = pwB; K = 64;  N = 64;  base = 0; }
  else if (tile < 24)  { W = wq; out = wqB; K = 64;  N = 64;  base = 8; }
  else if (tile < 40)  { W = wk; out = wkB; K = 64;  N = 64;  base = 24; }
  else if (tile < 56)  { W = wv; out = wvB; K = 64;  N = 64;  base = 40; }
  else if (tile < 72)  { W = wo; out = woB; K = 64;  N = 64;  base = 56; }
  else if (tile < 136) { W = w1; out = w1B; K = 64;  N = 256; base = 72; }
  else if (tile < 200) { W = w2; out = w2B; K = 256; N = 64;  base = 136; }
  else return;
  int lt = tile - base;
  int KT = K / 32, NT = N / 16;
  int nt = lt % NT; lt /= NT;
  int kt = lt % KT; lt /= KT;
  int m = lt;
  const float* Wm = W + (size_t)m * K * N;
  int kbase = kt * 32 + ((lane >> 4) * 8);
  int n = nt * 16 + (lane & 15);
  short v[8];
#pragma unroll
  for (int j = 0; j < 8; ++j) v[j] = f2b(Wm[(size_t)(kbase + j) * N + n]);
  *(bf16x8*)(out + ((size_t)(tile - base) * 64 + lane) * 8) = *(bf16x8*)v;
}

// fp32 table -> packed bf16 pairs, fused with dst-degree histogram and
// seq-referenced-node flagging (avgh is only read at flagged nodes).
__global__ void cvt_hist(const float* __restrict__ in, unsigned* __restrict__ out,
                         int n32, const int* __restrict__ dst, int* __restrict__ cnt,
                         int E, const int* __restrict__ seq,
                         unsigned char* __restrict__ flags, int BS) {
  int i = blockIdx.x * blockDim.x + threadIdx.x;
  if (i < n32) {
    float2 f = ((const float2*)in)[i];
    out[i] = packb(f.x, f.y);
  }
  if (i < E) atomicAdd(&cnt[dst[i]], 1);
  if (i < BS) flags[seq[i]] = 1;
}

// ---------------------------------------------------------------------------
// GNN CSR scan/build (unchanged)
// ---------------------------------------------------------------------------
__global__ void gnn_chunk_sums(const int* __restrict__ cnt, int* __restrict__ bsum) {
  __shared__ int ssum;
  if (threadIdx.x == 0) ssum = 0;
  __syncthreads();
  int base = blockIdx.x * 1024 + threadIdx.x * 4;
  int s = cnt[base] + cnt[base + 1] + cnt[base + 2] + cnt[base + 3];
#pragma unroll
  for (int o = 32; o > 0; o >>= 1) s += __shfl_xor(s, o, 64);
  if ((threadIdx.x & 63) == 0) atomicAdd(&ssum, s);
  __syncthreads();
  if (threadIdx.x == 0) bsum[blockIdx.x] = ssum;
}

__global__ void gnn_scan_bsum(int* __restrict__ bsum, int nch) {
  __shared__ int sb[128];
  int t = threadIdx.x;
  if (t < nch) sb[t] = bsum[t];
  __syncthreads();
  if (t == 0) {
    int a = 0;
    for (int i = 0; i < nch; ++i) { int v = sb[i]; sb[i] = a; a += v; }
  }
  __syncthreads();
  if (t < nch) bsum[t] = sb[t];
}

__global__ void gnn_chunk_scan(const int* __restrict__ cnt, const int* __restrict__ bofs,
                               int* __restrict__ rp, int* __restrict__ wp, int Nn) {
  __shared__ int wsum[4];
  int t = threadIdx.x, lane = t & 63, wv = t >> 6;
  int base = blockIdx.x * 1024 + t * 4;
  int c0 = cnt[base], c1 = cnt[base + 1], c2 = cnt[base + 2], c3 = cnt[base + 3];
  int s = c0 + c1 + c2 + c3;
  int x = s;
#pragma unroll
  for (int o = 1; o < 64; o <<= 1) {
    int y = __shfl_up(x, o, 64);
    if (lane >= o) x += y;
  }
  if (lane == 63) wsum[wv] = x;
  __syncthreads();
  int wo = 0;
#pragma unroll
  for (int i = 0; i < 4; ++i) if (i < wv) wo += wsum[i];
  int excl = bofs[blockIdx.x] + wo + (x - s);
  int p[4];
  p[0] = excl; p[1] = p[0] + c0; p[2] = p[1] + c1; p[3] = p[2] + c2;
#pragma unroll
  for (int j = 0; j < 4; ++j) {
    int idx = base + j;
    if (idx <= Nn) rp[idx] = p[j];
    if (idx < Nn) wp[idx] = p[j];
  }
}

__global__ void gnn_build(const int* __restrict__ src, const int* __restrict__ dst,
                          const float* __restrict__ ew, int* __restrict__ wp,
                          int2* __restrict__ ep, int E) {
  int e = blockIdx.x * blockDim.x + threadIdx.x;
  if (e >= E) return;
  int pos = atomicAdd(&wp[dst[e]], 1);
  ep[pos] = make_int2(src[e], __float_as_int(ew[e]));
}

// ---------------------------------------------------------------------------
// Gather kernels, 8-slot wave-per-node version.
// lane = slot*8 + g: slot walks edges beg+slot, beg+slot+8, ...; lane g
// reads uint4 (8 bf16 dims) of the neighbor row -> 8 rows in flight/wave,
// per-lane dependent chain ceil(deg/8). ep reads coalesce to one 64B line.
// ---------------------------------------------------------------------------
__global__ void gnn_gather1(const unsigned* __restrict__ xinh,
                            const int* __restrict__ rp, const int2* __restrict__ ep,
                            unsigned* __restrict__ xouth, int Nn) {
  int n = blockIdx.x * 4 + (threadIdx.x >> 6);
  if (n >= Nn) return;
  int lane = threadIdx.x & 63;
  int slot = lane >> 3;
  int g = lane & 7;
  int beg = rp[n], end = rp[n + 1];
  float a[8] = {0.f, 0.f, 0.f, 0.f, 0.f, 0.f, 0.f, 0.f};
  for (int e = beg + slot; e < end; e += 8) {
    int2 ee = ep[e];
    float w = __int_as_float(ee.y);
    uint4 p = *(const uint4*)(xinh + (size_t)ee.x * 32 + g * 4);
    a[0] += b2f((short)(p.x & 0xFFFF)) * w;
    a[1] += b2f((short)(p.x >> 16)) * w;
    a[2] += b2f((short)(p.y & 0xFFFF)) * w;
    a[3] += b2f((short)(p.y >> 16)) * w;
    a[4] += b2f((short)(p.z & 0xFFFF)) * w;
    a[5] += b2f((short)(p.z >> 16)) * w;
    a[6] += b2f((short)(p.w & 0xFFFF)) * w;
    a[7] += b2f((short)(p.w >> 16)) * w;
  }
#pragma unroll
  for (int o = 8; o < 64; o <<= 1)
#pragma unroll
    for (int j = 0; j < 8; ++j) a[j] += __shfl_xor(a[j], o, 64);
  if (slot == 0) {
    uint4 o4;
    o4.x = packb(a[0], a[1]);
    o4.y = packb(a[2], a[3]);
    o4.z = packb(a[4], a[5]);
    o4.w = packb(a[6], a[7]);
    *(uint4*)(xouth + (size_t)n * 32 + g * 4) = o4;
  }
}

__global__ void gnn_gather_avg(const unsigned* __restrict__ x1h,
                               const int* __restrict__ rp, const int2* __restrict__ ep,
                               const float* __restrict__ gnn,
                               unsigned* __restrict__ avgh, int Nn,
                               const unsigned char* __restrict__ flags) {
  int n = blockIdx.x * 4 + (threadIdx.x >> 6);
  if (n >= Nn) return;
  if (!flags[n]) return;   // avgh[n] is never read by the transformer
  int lane = threadIdx.x & 63;
  int slot = lane >> 3;
  int g = lane & 7;
  int beg = rp[n], end = rp[n + 1];
  float a[8] = {0.f, 0.f, 0.f, 0.f, 0.f, 0.f, 0.f, 0.f};
  for (int e = beg + slot; e < end; e += 8) {
    int2 ee = ep[e];
    float w = __int_as_float(ee.y);
    uint4 p = *(const uint4*)(x1h + (size_t)ee.x * 32 + g * 4);
    a[0] += b2f((short)(p.x & 0xFFFF)) * w;
    a[1] += b2f((short)(p.x >> 16)) * w;
    a[2] += b2f((short)(p.y & 0xFFFF)) * w;
    a[3] += b2f((short)(p.y >> 16)) * w;
    a[4] += b2f((short)(p.z & 0xFFFF)) * w;
    a[5] += b2f((short)(p.z >> 16)) * w;
    a[6] += b2f((short)(p.w & 0xFFFF)) * w;
    a[7] += b2f((short)(p.w >> 16)) * w;
  }
#pragma unroll
  for (int o = 8; o < 64; o <<= 1)
#pragma unroll
    for (int j = 0; j < 8; ++j) a[j] += __shfl_xor(a[j], o, 64);
  if (slot == 0) {
    uint4 own = *(const uint4*)(x1h + (size_t)n * 32 + g * 4);
    float4 g0 = *(const float4*)(gnn + (size_t)n * 64 + g * 8);
    float4 g1 = *(const float4*)(gnn + (size_t)n * 64 + g * 8 + 4);
    float v0 = (g0.x + b2f((short)(own.x & 0xFFFF)) + a[0]) * (1.f / 3.f);
    float v1 = (g0.y + b2f((short)(own.x >> 16)) + a[1]) * (1.f / 3.f);
    float v2 = (g0.z + b2f((short)(own.y & 0xFFFF)) + a[2]) * (1.f / 3.f);
    float v3 = (g0.w + b2f((short)(own.y >> 16)) + a[3]) * (1.f / 3.f);
    float v4 = (g1.x + b2f((short)(own.z & 0xFFFF)) + a[4]) * (1.f / 3.f);
    float v5 = (g1.y + b2f((short)(own.z >> 16)) + a[5]) * (1.f / 3.f);
    float v6 = (g1.z + b2f((short)(own.w & 0xFFFF)) + a[6]) * (1.f / 3.f);
    float v7 = (g1.w + b2f((short)(own.w >> 16)) + a[7]) * (1.f / 3.f);
    uint4 o4;
    o4.x = packb(v0, v1);
    o4.y = packb(v2, v3);
    o4.z = packb(v4, v5);
    o4.w = packb(v6, v7);
    *(uint4*)(avgh + (size_t)n * 32 + g * 4) = o4;
  }
}

// fallback helpers
__global__ void gnn_scatter(const float* __restrict__ xin,
                            const int* __restrict__ src,
                            const int* __restrict__ dst,
                            const float* __restrict__ ew,
                            float* __restrict__ xout, int E) {
  int gid = blockIdx.x * blockDim.x + threadIdx.x;
  int e = gid >> 6;
  int d = gid & 63;
  if (e >= E) return;
  atomicAdd(&xout[(size_t)dst[e] * SD + d], xin[(size_t)src[e] * SD + d] * ew[e]);
}
__global__ void avg_from_f32(const float* __restrict__ gnn, const float* __restrict__ g1,
                             const float* __restrict__ g2, unsigned* __restrict__ avgh,
                             int n32) {
  int i = blockIdx.x * blockDim.x + threadIdx.x;
  if (i >= n32) return;
  float2 a = ((const float2*)gnn)[i];
  float2 b = ((const float2*)g1)[i];
  float2 c = ((const float2*)g2)[i];
  avgh[i] = packb((a.x + b.x + c.x) * (1.f / 3.f), (a.y + b.y + c.y) * (1.f / 3.f));
}

// ---------------------------------------------------------------------------
// MFMA transformer, row-ownership version (unchanged from R12).
// ---------------------------------------------------------------------------
__global__ __launch_bounds__(256, 3)
void seq_transformer(const int* __restrict__ seq, const int* __restrict__ lengths,
                     const float* __restrict__ bert, const short* __restrict__ avgh,
                     const float* __restrict__ pbias, const float* __restrict__ pos,
                     const short* __restrict__ pwB, const short* __restrict__ wqB,
                     const short* __restrict__ wkB, const short* __restrict__ wvB,
                     const short* __restrict__ woB, const short* __restrict__ w1B,
                     const short* __restrict__ w2B,
                     const float* __restrict__ b1, const float* __restrict__ b2,
                     const float* __restrict__ ln1g, const float* __restrict__ ln1b,
                     const float* __restrict__ ln2g, const float* __restrict__ ln2b,
                     const float* __restrict__ lnfg, const float* __restrict__ lnfb,
                     float* __restrict__ out) {
  __shared__ short xh[64 * PH];   // x
  __shared__ short qh[64 * PH];   // Q -> ctx -> ffn-h (own rows only)
  __shared__ short kh[64 * PH];   // K (cross-wave read)
  __shared__ short vt[64 * PH];   // V^T (cross-wave read)
  __shared__ short s0[64 * PH];   // P (own rows only; softmax is in-register)
  __shared__ int   sidx[64];

  const int t = threadIdx.x;
  const int lane = t & 63;
  const int mt = t >> 6;
  const int quad = lane >> 4;
  const int c0 = lane & 15;
  const int b = blockIdx.x;
  const int arow = mt * 16 + c0;   // own-row index for A-frags

  if (t < 64) sidx[t] = (t < SS) ? seq[b * SS + t] : 0;
  __syncthreads();   // barrier 1 (sidx)

  const int len = lengths[b];
  const float alpha = (len <= 10) ? 0.3f : ((len >= 50) ? 0.7f : 0.5f);
  const float isq = 0.17677669529663687f;  // 1/sqrt(32)

  // key mask bias per nt-tile (constant across layers/heads): key = nt*16+c0
  float kbias[4];
#pragma unroll
  for (int nt = 0; nt < 4; ++nt) {
    int key = nt * 16 + c0;
    kbias[nt] = (key < SS && sidx[key] != 0) ? 0.f : -1e9f;
  }

  // ---- phase 0a: fused GNN-average rows (own rows) -> qh
#pragma unroll
  for (int ir = 0; ir < 16; ++ir) {
    int s = mt * 16 + ir;
    short v = 0;
    if (s < SS) v = avgh[(size_t)sidx[s] * SD + lane];
    qh[s * PH + lane] = v;
  }

  // ---- phase 0b: gnn projection + blend + pos -> xh (own rows; no barrier:
  //      qh own rows written by this wave)
  {
    f32x4 o4[4];
    mm64(qh, pwB, arow, quad, lane, o4);
#pragma unroll
    for (int nt = 0; nt < 4; ++nt) {
      int c = nt * 16 + c0;
      float pbv = pbias[c];
#pragma unroll
      for (int r = 0; r < 4; ++r) {
        int row = mt * 16 + quad * 4 + r;
        short ov = 0;
        if (row < SS) {
          float g = o4[nt][r] + pbv;
          float xv = alpha * bert[(size_t)sidx[row] * SD + c] +
                     (1.f - alpha) * g + pos[row * SD + c];
          ov = f2b(xv);
        }
        xh[row * PH + c] = ov;
      }
    }
  }

#pragma unroll 1
  for (int blk = 0; blk < NBLK; ++blk) {
    const short* Wq = wqB + blk * 4096;
    const short* Wk = wkB + blk * 4096;
    const short* Wv = wvB + blk * 4096;
    const short* Wo = woB + blk * 4096;
    const short* W1 = w1B + blk * 16384;
    const short* W2 = w2B + blk * 16384;

    __syncthreads();   // layer-top: kh/vt safe to rewrite (prev readers done)

    // ---- Q -> qh, K -> kh (own rows), V -> vt (own seq-columns, transposed)
    {
      f32x4 o4[4];
      mm64(xh, Wq, arow, quad, lane, o4);
#pragma unroll
      for (int nt = 0; nt < 4; ++nt) {
        int c = nt * 16 + c0;
#pragma unroll
        for (int r = 0; r < 4; ++r) qh[(mt * 16 + quad * 4 + r) * PH + c] = f2b(o4[nt][r]);
      }
      mm64(xh, Wk, arow, quad, lane, o4);
#pragma unroll
      for (int nt = 0; nt < 4; ++nt) {
        int c = nt * 16 + c0;
#pragma unroll
        for (int r = 0; r < 4; ++r) kh[(mt * 16 + quad * 4 + r) * PH + c] = f2b(o4[nt][r]);
      }
      mm64(xh, Wv, arow, quad, lane, o4);
#pragma unroll
      for (int nt = 0; nt < 4; ++nt) {
        int dim = nt * 16 + c0;
        unsigned p0 = packb(o4[nt][0], o4[nt][1]);
        unsigned p1 = packb(o4[nt][2], o4[nt][3]);
        *(uint2*)(vt + (size_t)dim * PH + mt * 16 + quad * 4) = make_uint2(p0, p1);
      }
    }
    __syncthreads();   // kh/vt visible to all waves

    // ---- per-head: scores -> in-register softmax -> P -> ctx (no barriers)
#pragma unroll
    for (int h = 0; h < 2; ++h) {
      // scores for own q-rows; q-row (quad,r)'s 64 keys live across the
      // quad's 16 lanes (c0) x 4 regs (nt) -> intra-quad reductions.
      {
        bf16x8 aq = *(const bf16x8*)(qh + arow * PH + h * 32 + quad * 8);
        float p[4][4];   // [nt][r]
        float mx[4], sm[4];
#pragma unroll
        for (int nt = 0; nt < 4; ++nt) {
          int key = nt * 16 + c0;
          bf16x8 bk = *(const bf16x8*)(kh + key * PH + h * 32 + quad * 8);
          f32x4 acc = {0.f, 0.f, 0.f, 0.f};
          acc = __builtin_amdgcn_mfma_f32_16x16x32_bf16(aq, bk, acc, 0, 0, 0);
#pragma unroll
          for (int r = 0; r < 4; ++r) p[nt][r] = fmaf(acc[r], isq, kbias[nt]);
        }
#pragma unroll
        for (int r = 0; r < 4; ++r)
          mx[r] = fmaxf(fmaxf(p[0][r], p[1][r]), fmaxf(p[2][r], p[3][r]));
#pragma unroll
        for (int o = 1; o < 16; o <<= 1)
#pragma unroll
          for (int r = 0; r < 4; ++r) mx[r] = fmaxf(mx[r], __shfl_xor(mx[r], o, 64));
#pragma unroll
        for (int r = 0; r < 4; ++r) sm[r] = 0.f;
#pragma unroll
        for (int nt = 0; nt < 4; ++nt)
#pragma unroll
          for (int r = 0; r < 4; ++r) {
            float e = __expf(p[nt][r] - mx[r]);
            p[nt][r] = e;
            sm[r] += e;
          }
#pragma unroll
        for (int o = 1; o < 16; o <<= 1)
#pragma unroll
          for (int r = 0; r < 4; ++r) sm[r] += __shfl_xor(sm[r], o, 64);
#pragma unroll
        for (int r = 0; r < 4; ++r) {
          float inv = __builtin_amdgcn_rcpf(sm[r]);
          int q = mt * 16 + quad * 4 + r;
#pragma unroll
          for (int nt = 0; nt < 4; ++nt)
            s0[q * PH + nt * 16 + c0] = f2b(p[nt][r] * inv);
        }
      }
      // ctx_h = P V_h -> overwrite qh own rows, cols h*32..h*32+31
      {
        bf16x8 a0 = *(const bf16x8*)(s0 + arow * PH + quad * 8);
        bf16x8 a1 = *(const bf16x8*)(s0 + arow * PH + 32 + quad * 8);
#pragma unroll
        for (int nt = 0; nt < 2; ++nt) {
          int dim = h * 32 + nt * 16 + c0;
          bf16x8 b0 = *(const bf16x8*)(vt + (size_t)dim * PH + quad * 8);
          bf16x8 b1v = *(const bf16x8*)(vt + (size_t)dim * PH + 32 + quad * 8);
          f32x4 acc = {0.f, 0.f, 0.f, 0.f};
          acc = __builtin_amdgcn_mfma_f32_16x16x32_bf16(a0, b0, acc, 0, 0, 0);
          acc = __builtin_amdgcn_mfma_f32_16x16x32_bf16(a1, b1v, acc, 0, 0, 0);
#pragma unroll
          for (int r = 0; r < 4; ++r)
            qh[(mt * 16 + quad * 4 + r) * PH + dim] = f2b(acc[r]);
        }
      }
    }

    // ---- O-projection + residual + LN1 -> xh (own rows)
    {
      f32x4 o4[4];
      mm64(qh, Wo, arow, quad, lane, o4);
      ln_epilogue(o4, xh, ln1g + blk * SD, ln1b + blk * SD, nullptr, mt, quad, c0);
    }

    // ---- FFN, own rows, no barriers (intra-wave LDS ordering)
    f32x4 facc[4];
#pragma unroll
    for (int nt = 0; nt < 4; ++nt) facc[nt] = (f32x4){0.f, 0.f, 0.f, 0.f};
#pragma unroll 1
    for (int c = 0; c < 4; ++c) {
      {
        bf16x8 a0 = *(const bf16x8*)(xh + arow * PH + quad * 8);
        bf16x8 a1 = *(const bf16x8*)(xh + arow * PH + 32 + quad * 8);
#pragma unroll
        for (int nt = 0; nt < 4; ++nt) {
          int ntg = c * 4 + nt;
          f32x4 acc = {0.f, 0.f, 0.f, 0.f};
          acc = __builtin_amdgcn_mfma_f32_16x16x32_bf16(a0, ldB(W1, 0 * 16 + ntg, lane), acc, 0, 0, 0);
          acc = __builtin_amdgcn_mfma_f32_16x16x32_bf16(a1, ldB(W1, 1 * 16 + ntg, lane), acc, 0, 0, 0);
          int cc = nt * 16 + c0;
          float b1v = b1[blk * 256 + c * 64 + cc];
#pragma unroll
          for (int r = 0; r < 4; ++r)
            qh[(mt * 16 + quad * 4 + r) * PH + cc] = f2b(gelu_fast(acc[r] + b1v));
        }
      }
      {
        bf16x8 a0 = *(const bf16x8*)(qh + arow * PH + quad * 8);
        bf16x8 a1 = *(const bf16x8*)(qh + arow * PH + 32 + quad * 8);
#pragma unroll
        for (int nt = 0; nt < 4; ++nt) {
          facc[nt] = __builtin_amdgcn_mfma_f32_16x16x32_bf16(a0, ldB(W2, (2 * c) * 4 + nt, lane), facc[nt], 0, 0, 0);
          facc[nt] = __builtin_amdgcn_mfma_f32_16x16x32_bf16(a1, ldB(W2, (2 * c + 1) * 4 + nt, lane), facc[nt], 0, 0, 0);
        }
      }
    }

    // ---- residual + b2 + LN2 -> xh (own rows)
    ln_epilogue(facc, xh, ln2g + blk * SD, ln2b + blk * SD, b2 + blk * SD, mt, quad, c0);
  }
  __syncthreads();   // final: xh fully written by all waves

  // ---- final LN + gather row (lengths-1)
  if (mt == 0) {
    int sl = len - 1;
    float val = b2f(xh[sl * PH + lane]);
    float2 ss = wred_sum2(val, val * val);
    float m = ss.x * (1.f / 64);
    float var = fmaxf(ss.y * (1.f / 64) - m * m, 0.f);
    float rs = rsqrtf(var + 1e-5f);
    out[b * SD + lane] = (val - m) * rs * lnfg[lane] + lnfb[lane];
  }
}

// ---------------------------------------------------------------------------
extern "C" void kernel_launch(void* const* d_in, const int* in_sizes, int n_in,
                              void* d_out, int out_size, void* d_ws, size_t ws_size,
                              hipStream_t stream) {
  const int*   seq   = (const int*)d_in[0];
  const int*   lens  = (const int*)d_in[1];
  const int*   ei    = (const int*)d_in[2];
  const float* ew    = (const float*)d_in[3];
  const float* bert  = (const float*)d_in[4];
  const float* gnn   = (const float*)d_in[5];
  const float* pw    = (const float*)d_in[6];
  const float* pb    = (const float*)d_in[7];
  const float* pos   = (const float*)d_in[8];
  const float* wq    = (const float*)d_in[9];
  const float* wk    = (const float*)d_in[10];
  const float* wv    = (const float*)d_in[11];
  const float* wo    = (const float*)d_in[12];
  const float* w1    = (const float*)d_in[13];
  const float* b1    = (const float*)d_in[14];
  const float* w2    = (const float*)d_in[15];
  const float* b2    = (const float*)d_in[16];
  const float* ln1g  = (const float*)d_in[17];
  const float* ln1b  = (const float*)d_in[18];
  const float* ln2g  = (const float*)d_in[19];
  const float* ln2b  = (const float*)d_in[20];
  const float* lnfg  = (const float*)d_in[21];
  const float* lnfb  = (const float*)d_in[22];
  float* out = (float*)d_out;

  const int E = in_sizes[2] / 2;          // 1,000,000
  const int B = in_sizes[0] / SS;         // 1024
  const int N = in_sizes[4] / SD;         // 100,001
  const int BS = B * SS;                  // 51,200 seq entries

  const int* esrc = ei;
  const int* edst = ei + E;

  // ---- workspace layout
  short* pwB = (short*)d_ws;              // 4096 halves
  short* wqB = pwB + 4096;                // 8192
  short* wkB = wqB + 8192;
  short* wvB = wkB + 8192;
  short* woB = wvB + 8192;
  short* w1B = woB + 8192;                // 32768
  short* w2B = w1B + 32768;               // 32768
  unsigned* gnnh = (unsigned*)(w2B + 32768);   // N*32 uints (bf16 pairs)
  unsigned* g1xh = gnnh + (size_t)N * 32;
  unsigned* avgh = g1xh + (size_t)N * 32;
  const int NCH = (N + 1023) >> 10;
  const int PADN = NCH << 10;
  int* cnt  = (int*)(avgh + (size_t)N * 32);
  const int NF = (N + 255) & ~255;        // flag bytes, padded
  unsigned char* flags = (unsigned char*)(cnt + PADN);
  int* bsum = (int*)(flags + NF);
  int* rp   = bsum + 128;
  int* wp   = rp + (N + 1);
  int2* ep = (int2*)((((size_t)(wp + N)) + 15) & ~(size_t)15);
  size_t need = (size_t)((char*)(ep + E) - (char*)d_ws);

  // fallback fp32 tables (overlay the CSR/scan region)
  float* g1x = (float*)cnt;
  float* g2x = g1x + (size_t)N * SD;
  size_t need_fb = (size_t)((char*)(g2x + (size_t)N * SD) - (char*)d_ws);

  // ---- weight prep (1 launch)
  prep_all<<<50, 256, 0, stream>>>(pw, wq, wk, wv, wo, w1, w2,
                                   pwB, wqB, wkB, wvB, woB, w1B, w2B);

  const int n32 = N * 32;
  if (ws_size >= need && NCH <= 128) {
    hipMemsetAsync(cnt, 0, (size_t)PADN * sizeof(int) + NF, stream);
    cvt_hist<<<(n32 + 255) / 256, 256, 0, stream>>>(gnn, gnnh, n32, edst, cnt, E,
                                                    seq, flags, BS);
    gnn_chunk_sums<<<NCH, 256, 0, stream>>>(cnt, bsum);
    gnn_scan_bsum<<<1, 128, 0, stream>>>(bsum, NCH);
    gnn_chunk_scan<<<NCH, 256, 0, stream>>>(cnt, bsum, rp, wp, N);
    gnn_build<<<(E + 255) / 256, 256, 0, stream>>>(esrc, edst, ew, wp, ep, E);
    const int nb = (N + 3) / 4;
    gnn_gather1<<<nb, 256, 0, stream>>>(gnnh, rp, ep, g1xh, N);
    gnn_gather_avg<<<nb, 256, 0, stream>>>(g1xh, rp, ep, gnn, avgh, N, flags);
  } else if (ws_size >= need_fb) {
    hipMemsetAsync(g1x, 0, (size_t)2 * N * SD * sizeof(float), stream);
    const long total = (long)E * 64;
    const int sblocks = (int)((total + 255) / 256);
    gnn_scatter<<<sblocks, 256, 0, stream>>>(gnn, esrc, edst, ew, g1x, E);
    gnn_scatter<<<sblocks, 256, 0, stream>>>(g1x, esrc, edst, ew, g2x, E);
    avg_from_f32<<<(n32 + 255) / 256, 256, 0, stream>>>(gnn, g1x, g2x, avgh, n32);
  }

  seq_transformer<<<B, 256, 0, stream>>>(
      seq, lens, bert, (const short*)avgh, pb, pos,
      pwB, wqB, wkB, wvB, woB, w1B, w2B,
      b1, b2, ln1g, ln1b, ln2g, ln2b, lnfg, lnfb, out);
}